// Round 12
// baseline (157.378 us; speedup 1.0000x reference)
//
#include <hip/hip_runtime.h>
#include <stdint.h>

#define N_ROWS 8192
#define C_IN   4096
#define C_OUT  4096
#define NCHUNK (C_IN / 64)     // 64 chunks of BK=64 (one 32x32x64 MFMA K-slab)
#define MT4    65536           // bytes per 32-row slab in fp4 frag file

typedef int   v4i  __attribute__((ext_vector_type(4)));
typedef float v16f __attribute__((ext_vector_type(16)));

// ======================================================================
// pack (LDS-transpose): f32 -> fp4 e2m1 sign (+1 -> 0x2, -1 -> 0xA),
// frag-ordered. Verified on HW (rounds 6-11). Unchanged.
// ======================================================================
__global__ void pack_all_kernel(const float* __restrict__ x,
                                const float* __restrict__ w,
                                uint8_t* __restrict__ xf,
                                uint8_t* __restrict__ wf,
                                float* __restrict__ partials) {
    __shared__ __align__(16) uint16_t tile16[4096];   // 8 KB
    __shared__ float sacc[4];

    const int b = blockIdx.x;
    const float* src; uint8_t* dst; int slab;
    if (b < 2048) { src = x; dst = xf; slab = b; }        // x: 256 mt x 8 cg
    else          { src = w; dst = wf; slab = b - 2048; } // w: 128 mt x 8 cg
    const int mt = slab >> 3, cg = slab & 7;

    const int t = threadIdx.x;
    const int r = t >> 3, lc = t & 7;

    const float4* base = (const float4*)(src + (size_t)(mt * 32 + r) * C_IN + cg * 512) + lc;
    float acc = 0.f;
#pragma unroll
    for (int it = 0; it < 16; ++it) {
        float4 v = base[it * 8];
        uint16_t nv = (uint16_t)((v.x > 0.f ? 0x2u : 0xAu)
                               | (v.y > 0.f ? 0x2u : 0xAu) << 4
                               | (v.z > 0.f ? 0x2u : 0xAu) << 8
                               | (v.w > 0.f ? 0x2u : 0xAu) << 12);
        acc += fabsf(v.x) + fabsf(v.y) + fabsf(v.z) + fabsf(v.w);
        tile16[it * 256 + t] = nv;
    }
    __syncthreads();
    uint4* gout = (uint4*)(dst + (size_t)mt * MT4 + (size_t)cg * 8192);
    const uint4* lin = (const uint4*)tile16;
#pragma unroll
    for (int p = 0; p < 2; ++p) gout[p * 256 + t] = lin[p * 256 + t];

    for (int off = 32; off > 0; off >>= 1) acc += __shfl_down(acc, off, 64);
    const int lane = t & 63, wv = t >> 6;
    if (lane == 0) sacc[wv] = acc;
    __syncthreads();
    if (t == 0) {
        float s = 0.f;
        for (int i = 0; i < 4; ++i) s += sacc[i];
        partials[b] = s;
    }
}

// ---- deterministic final reduction -> alpha*betta ----
__global__ void finalize_kernel(const float* __restrict__ part_x, int nx,
                                const float* __restrict__ part_w, int nw,
                                float* __restrict__ out_ab) {
    __shared__ float s[256];
    float ax = 0.f;
    for (int i = threadIdx.x; i < nx; i += 256) ax += part_x[i];
    s[threadIdx.x] = ax; __syncthreads();
    for (int st = 128; st > 0; st >>= 1) {
        if (threadIdx.x < st) s[threadIdx.x] += s[threadIdx.x + st];
        __syncthreads();
    }
    float sumx = s[0];
    __syncthreads();
    float aw = 0.f;
    for (int i = threadIdx.x; i < nw; i += 256) aw += part_w[i];
    s[threadIdx.x] = aw; __syncthreads();
    for (int st = 128; st > 0; st >>= 1) {
        if (threadIdx.x < st) s[threadIdx.x] += s[threadIdx.x + st];
        __syncthreads();
    }
    if (threadIdx.x == 0) {
        float sumw = s[0];
        float alpha = sumw / (float)((long long)C_OUT * C_IN);
        float betta = sumx / (float)((long long)N_ROWS * C_IN);
        out_ab[0] = alpha * betta;
    }
}

// ======================================================================
// MX-FP4 MFMA GEMM, T14 reg-staged LDS (global->VGPR->ds_write_b128):
// tests the "global_load_lds write path serializes the LDS pipe" theory.
// 256x256 tile, 8 waves (2x4), per-wave 128x64 (4m x 2n, 128 acc regs),
// 4 LDS buffers (64 KB). Per body(c):
//   issue global loads chunk c+2 -> Gnext (latency hidden over 1 body)
//   ds_write Gcur (chunk c+1) -> buf[(c+1)&3]  (compiler inserts vmcnt)
//   lgkm(0); barrier  (publishes c+1)
//   read frags chunk c+1 into other set; 8 MFMAs on chunk c.
// ======================================================================
#define MF(a, b, c) \
    __builtin_amdgcn_mfma_scale_f32_32x32x64_f8f6f4( \
        __builtin_shufflevector((a), (a), 0, 1, 2, 3, -1, -1, -1, -1), \
        __builtin_shufflevector((b), (b), 0, 1, 2, 3, -1, -1, -1, -1), \
        (c), 4, 4, 0, 127, 0, 127)

__launch_bounds__(512, 2)
__global__ void xnor_gemm_fp4(const uint8_t* __restrict__ Afrag,
                              const uint8_t* __restrict__ Bfrag,
                              const float* __restrict__ bias,
                              const float* __restrict__ ab_ptr,
                              float* __restrict__ out) {
    __shared__ __align__(16) uint8_t lds[4][16384];  // 4 bufs x (A 8K | B 8K)

    const int t    = threadIdx.x;
    const int lane = t & 63;
    const int hi   = lane >> 5;
    const int r    = lane & 31;
    const int wid  = t >> 6;
    const int wr   = wid >> 2;   // 0..1 (M waves)
    const int wc   = wid & 3;    // 0..3 (N waves)

    // XCD-aware swizzle over 512 blocks (divisible by 8)
    const int id  = blockIdx.x;
    const int swz = (id & 7) * 64 + (id >> 3);
    const int brow = (swz >> 4) * 256;
    const int bcol = (swz & 15) * 256;

    const uint8_t* Abase = Afrag + (size_t)(brow >> 5) * MT4;
    const uint8_t* Bbase = Bfrag + (size_t)(bcol >> 5) * MT4;
    // per-thread staging piece: slab = t>>6, frag-lane = t&63 (16 B)
    const size_t soff = (size_t)(t >> 6) * MT4 + (size_t)(t & 63) * 16;

#define GLOAD(GA, GB, c)                                                    \
    do {                                                                    \
        GA = *(const uint4*)(Abase + soff + (size_t)(c) * 1024);            \
        GB = *(const uint4*)(Bbase + soff + (size_t)(c) * 1024);            \
    } while (0)

#define SWRITE(GA, GB, BUF)                                                 \
    do {                                                                    \
        *(uint4*)(&lds[BUF][t * 16])        = GA;                           \
        *(uint4*)(&lds[BUF][8192 + t * 16]) = GB;                           \
    } while (0)

#define LOADFRAGS(AS, BS, BUF)                                                        \
    do {                                                                              \
        AS[0] = *(const v4i*)(&lds[BUF][((wr * 4 + 0) * 64 + lane) * 16]);            \
        AS[1] = *(const v4i*)(&lds[BUF][((wr * 4 + 1) * 64 + lane) * 16]);            \
        AS[2] = *(const v4i*)(&lds[BUF][((wr * 4 + 2) * 64 + lane) * 16]);            \
        AS[3] = *(const v4i*)(&lds[BUF][((wr * 4 + 3) * 64 + lane) * 16]);            \
        BS[0] = *(const v4i*)(&lds[BUF][8192 + ((wc * 2 + 0) * 64 + lane) * 16]);     \
        BS[1] = *(const v4i*)(&lds[BUF][8192 + ((wc * 2 + 1) * 64 + lane) * 16]);     \
    } while (0)

#define DOMFMA(AS, BS)                                \
    do {                                              \
        __builtin_amdgcn_s_setprio(1);                \
        acc[0][0] = MF(AS[0], BS[0], acc[0][0]);      \
        acc[0][1] = MF(AS[0], BS[1], acc[0][1]);      \
        acc[1][0] = MF(AS[1], BS[0], acc[1][0]);      \
        acc[1][1] = MF(AS[1], BS[1], acc[1][1]);      \
        acc[2][0] = MF(AS[2], BS[0], acc[2][0]);      \
        acc[2][1] = MF(AS[2], BS[1], acc[2][1]);      \
        acc[3][0] = MF(AS[3], BS[0], acc[3][0]);      \
        acc[3][1] = MF(AS[3], BS[1], acc[3][1]);      \
        __builtin_amdgcn_s_setprio(0);                \
    } while (0)

    // BODY(c): CA/CB = frags(chunk c); WGA/WGB = G regs holding chunk c+1;
    // LGA/LGB = G regs to fill with chunk c+2; NA/NB = frag set for c+1.
#define BODY(cexp, CA, CB, NA, NB, WGA, WGB, LGA, LGB)                              \
    do {                                                                            \
        const int c_ = (cexp);                                                      \
        if (c_ + 2 < NCHUNK) GLOAD(LGA, LGB, c_ + 2);                               \
        if (c_ + 1 < NCHUNK) SWRITE(WGA, WGB, (c_ + 1) & 3);                        \
        asm volatile("s_waitcnt lgkmcnt(0)" ::: "memory");                          \
        __builtin_amdgcn_s_barrier();                                               \
        if (c_ + 1 < NCHUNK) LOADFRAGS(NA, NB, (c_ + 1) & 3);                       \
        DOMFMA(CA, CB);                                                             \
    } while (0)

    v16f acc[4][2] = {};
    v4i A0[4], B0[2], A1[4], B1[2];
    uint4 GaA, GaB, GbA, GbB;

    // prologue: load chunk0 + chunk1 to regs; write chunk0; publish; frags(0).
    GLOAD(GbA, GbB, 0);
    GLOAD(GaA, GaB, 1);
    SWRITE(GbA, GbB, 0);               // compiler waits vmcnt for Gb here
    asm volatile("s_waitcnt lgkmcnt(0)" ::: "memory");
    __builtin_amdgcn_s_barrier();
    LOADFRAGS(A0, B0, 0);

    for (int cb = 0; cb < NCHUNK; cb += 2) {
        BODY(cb + 0, A0, B0, A1, B1, GaA, GaB, GbA, GbB);  // write chunk c+1 (Ga), load c+2 -> Gb
        BODY(cb + 1, A1, B1, A0, B0, GbA, GbB, GaA, GaB);  // write chunk c+2 (Gb), load c+3 -> Ga
    }

    const float ab = ab_ptr[0];
#pragma unroll
    for (int m = 0; m < 4; ++m) {
#pragma unroll
        for (int n = 0; n < 2; ++n) {
            int col = bcol + wc * 64 + n * 32 + r;
            float bv = bias[col];
#pragma unroll
            for (int reg = 0; reg < 16; ++reg) {
                int rowf = (reg & 3) + 8 * (reg >> 2) + 4 * hi;   // C/D layout (shape-determined)
                int grow = brow + wr * 128 + m * 32 + rowf;
                out[(size_t)grow * C_OUT + col] = acc[m][n][reg] * ab + bv;
            }
        }
    }
#undef GLOAD
#undef SWRITE
#undef LOADFRAGS
#undef DOMFMA
#undef BODY
}

// ======================================================================
extern "C" void kernel_launch(void* const* d_in, const int* in_sizes, int n_in,
                              void* d_out, int out_size, void* d_ws, size_t ws_size,
                              hipStream_t stream) {
    const float* x    = (const float*)d_in[0];
    const float* w    = (const float*)d_in[1];
    const float* bias = (const float*)d_in[2];
    float* out = (float*)d_out;

    char* ws = (char*)d_ws;
    float* red      = (float*)ws;      // red[0] = alpha*betta
    float* partials = red + 16;        // 3072 partials (x: 0..2047, w: 2048..3071)
    uint8_t* xs  = (uint8_t*)(ws + 16384);             // 16 MB fp4 frag file (x)
    uint8_t* wsg = xs + (size_t)N_ROWS * C_IN / 2;     // 8 MB fp4 frag file (w)

    pack_all_kernel<<<3072, 256, 0, stream>>>(x, w, xs, wsg, partials);
    finalize_kernel<<<1, 256, 0, stream>>>(partials, 2048, partials + 2048, 1024, red);

    dim3 grid((N_ROWS / 256) * (C_OUT / 256));  // 512
    xnor_gemm_fp4<<<grid, 512, 0, stream>>>(xs, wsg, bias, red, out);
}

// Round 13
// 131.333 us; speedup vs baseline: 1.1983x; 1.1983x over previous
//
#include <hip/hip_runtime.h>
#include <stdint.h>

#define N_ROWS 8192
#define C_IN   4096
#define C_OUT  4096
#define NCHUNK (C_IN / 64)     // 64 chunks of BK=64 (one 32x32x64 MFMA K-slab)
#define MT4    65536           // bytes per 32-row slab in fp4 frag file

typedef int   v4i  __attribute__((ext_vector_type(4)));
typedef float v16f __attribute__((ext_vector_type(16)));

// ======================================================================
// pack (LDS-transpose): f32 -> fp4 e2m1 sign (+1 -> 0x2, -1 -> 0xA),
// frag-ordered. Verified on HW (rounds 6-12). Unchanged.
// ======================================================================
__global__ void pack_all_kernel(const float* __restrict__ x,
                                const float* __restrict__ w,
                                uint8_t* __restrict__ xf,
                                uint8_t* __restrict__ wf,
                                float* __restrict__ partials) {
    __shared__ __align__(16) uint16_t tile16[4096];   // 8 KB
    __shared__ float sacc[4];

    const int b = blockIdx.x;
    const float* src; uint8_t* dst; int slab;
    if (b < 2048) { src = x; dst = xf; slab = b; }        // x: 256 mt x 8 cg
    else          { src = w; dst = wf; slab = b - 2048; } // w: 128 mt x 8 cg
    const int mt = slab >> 3, cg = slab & 7;

    const int t = threadIdx.x;
    const int r = t >> 3, lc = t & 7;

    const float4* base = (const float4*)(src + (size_t)(mt * 32 + r) * C_IN + cg * 512) + lc;
    float acc = 0.f;
#pragma unroll
    for (int it = 0; it < 16; ++it) {
        float4 v = base[it * 8];
        uint16_t nv = (uint16_t)((v.x > 0.f ? 0x2u : 0xAu)
                               | (v.y > 0.f ? 0x2u : 0xAu) << 4
                               | (v.z > 0.f ? 0x2u : 0xAu) << 8
                               | (v.w > 0.f ? 0x2u : 0xAu) << 12);
        acc += fabsf(v.x) + fabsf(v.y) + fabsf(v.z) + fabsf(v.w);
        tile16[it * 256 + t] = nv;
    }
    __syncthreads();
    uint4* gout = (uint4*)(dst + (size_t)mt * MT4 + (size_t)cg * 8192);
    const uint4* lin = (const uint4*)tile16;
#pragma unroll
    for (int p = 0; p < 2; ++p) gout[p * 256 + t] = lin[p * 256 + t];

    for (int off = 32; off > 0; off >>= 1) acc += __shfl_down(acc, off, 64);
    const int lane = t & 63, wv = t >> 6;
    if (lane == 0) sacc[wv] = acc;
    __syncthreads();
    if (t == 0) {
        float s = 0.f;
        for (int i = 0; i < 4; ++i) s += sacc[i];
        partials[b] = s;
    }
}

// ---- deterministic final reduction -> alpha*betta ----
__global__ void finalize_kernel(const float* __restrict__ part_x, int nx,
                                const float* __restrict__ part_w, int nw,
                                float* __restrict__ out_ab) {
    __shared__ float s[256];
    float ax = 0.f;
    for (int i = threadIdx.x; i < nx; i += 256) ax += part_x[i];
    s[threadIdx.x] = ax; __syncthreads();
    for (int st = 128; st > 0; st >>= 1) {
        if (threadIdx.x < st) s[threadIdx.x] += s[threadIdx.x + st];
        __syncthreads();
    }
    float sumx = s[0];
    __syncthreads();
    float aw = 0.f;
    for (int i = threadIdx.x; i < nw; i += 256) aw += part_w[i];
    s[threadIdx.x] = aw; __syncthreads();
    for (int st = 128; st > 0; st >>= 1) {
        if (threadIdx.x < st) s[threadIdx.x] += s[threadIdx.x + st];
        __syncthreads();
    }
    if (threadIdx.x == 0) {
        float sumw = s[0];
        float alpha = sumw / (float)((long long)C_OUT * C_IN);
        float betta = sumx / (float)((long long)N_ROWS * C_IN);
        out_ab[0] = alpha * betta;
    }
}

// ======================================================================
// MX-FP4 MFMA GEMM — round-6 structure (the measured best: 78.4 us),
// with two deltas: (1) NO s_setprio (T5/m190: hurts lockstep GEMM;
// suspected phase-lockstep reinforcer), (2) shufflevector operand build
// (no zero-fill movs; verified r7-r12).
// 256x256 tile, 8 waves (2x4), per-wave 128x64 (4m x 2n, 128 acc regs).
// 4-deep LDS buffers (64 KB); stage chunk c+2; counted vmcnt(2);
// ONE barrier per chunk. All LDS reads base+lane*16: conflict-free.
// ======================================================================
#define MF(a, b, c) \
    __builtin_amdgcn_mfma_scale_f32_32x32x64_f8f6f4( \
        __builtin_shufflevector((a), (a), 0, 1, 2, 3, -1, -1, -1, -1), \
        __builtin_shufflevector((b), (b), 0, 1, 2, 3, -1, -1, -1, -1), \
        (c), 4, 4, 0, 127, 0, 127)

__launch_bounds__(512)
__global__ void xnor_gemm_fp4(const uint8_t* __restrict__ Afrag,
                              const uint8_t* __restrict__ Bfrag,
                              const float* __restrict__ bias,
                              const float* __restrict__ ab_ptr,
                              float* __restrict__ out) {
    __shared__ __align__(16) uint8_t lds[4][2][8192];  // 64 KB

    const int t    = threadIdx.x;
    const int lane = t & 63;
    const int hi   = lane >> 5;
    const int r    = lane & 31;
    const int wid  = t >> 6;
    const int wr   = wid >> 2;   // 0..1 (M waves)
    const int wc   = wid & 3;    // 0..3 (N waves)

    // XCD-aware swizzle over 512 blocks (divisible by 8)
    const int id  = blockIdx.x;
    const int swz = (id & 7) * 64 + (id >> 3);
    const int brow = (swz >> 4) * 256;
    const int bcol = (swz & 15) * 256;

    const uint8_t* Abase = Afrag + (size_t)(brow >> 5) * MT4;
    const uint8_t* Bbase = Bfrag + (size_t)(bcol >> 5) * MT4;
    const size_t soff = (size_t)(t >> 6) * MT4 + (size_t)(t & 63) * 16;

#define STG(BUF, c)                                                                     \
    do {                                                                                \
        size_t ka = (size_t)(c) * 1024;                                                 \
        __builtin_amdgcn_global_load_lds(                                               \
            (const __attribute__((address_space(1))) void*)(Abase + soff + ka),         \
            (__attribute__((address_space(3))) void*)(&lds[BUF][0][t * 16]), 16, 0, 0); \
        __builtin_amdgcn_global_load_lds(                                               \
            (const __attribute__((address_space(1))) void*)(Bbase + soff + ka),         \
            (__attribute__((address_space(3))) void*)(&lds[BUF][1][t * 16]), 16, 0, 0); \
    } while (0)

    v16f acc[4][2] = {};

    STG(0, 0); STG(1, 1);   // 4 loads in flight (A0,B0,A1,B1)

#pragma unroll 4
    for (int ck = 0; ck < NCHUNK; ++ck) {
        const int buf = ck & 3;
        if (ck < NCHUNK - 2) { asm volatile("s_waitcnt vmcnt(2)" ::: "memory"); }
        else                 { asm volatile("s_waitcnt vmcnt(0)" ::: "memory"); }
        __builtin_amdgcn_s_barrier();

        v4i a4[4], b4[2];
#pragma unroll
        for (int m = 0; m < 4; ++m)
            a4[m] = *(const v4i*)(&lds[buf][0][((wr * 4 + m) * 64 + lane) * 16]);
#pragma unroll
        for (int n = 0; n < 2; ++n)
            b4[n] = *(const v4i*)(&lds[buf][1][((wc * 2 + n) * 64 + lane) * 16]);

        if (ck + 2 < NCHUNK) STG((ck + 2) & 3, ck + 2);

#pragma unroll
        for (int m = 0; m < 4; ++m)
#pragma unroll
            for (int n = 0; n < 2; ++n)
                acc[m][n] = MF(a4[m], b4[n], acc[m][n]);
    }

    const float ab = ab_ptr[0];
#pragma unroll
    for (int m = 0; m < 4; ++m) {
#pragma unroll
        for (int n = 0; n < 2; ++n) {
            int col = bcol + wc * 64 + n * 32 + r;
            float bv = bias[col];
#pragma unroll
            for (int reg = 0; reg < 16; ++reg) {
                int rowf = (reg & 3) + 8 * (reg >> 2) + 4 * hi;   // C/D layout (shape-determined)
                int grow = brow + wr * 128 + m * 32 + rowf;
                out[(size_t)grow * C_OUT + col] = acc[m][n][reg] * ab + bv;
            }
        }
    }
#undef STG
}

// ======================================================================
extern "C" void kernel_launch(void* const* d_in, const int* in_sizes, int n_in,
                              void* d_out, int out_size, void* d_ws, size_t ws_size,
                              hipStream_t stream) {
    const float* x    = (const float*)d_in[0];
    const float* w    = (const float*)d_in[1];
    const float* bias = (const float*)d_in[2];
    float* out = (float*)d_out;

    char* ws = (char*)d_ws;
    float* red      = (float*)ws;      // red[0] = alpha*betta
    float* partials = red + 16;        // 3072 partials (x: 0..2047, w: 2048..3071)
    uint8_t* xs  = (uint8_t*)(ws + 16384);             // 16 MB fp4 frag file (x)
    uint8_t* wsg = xs + (size_t)N_ROWS * C_IN / 2;     // 8 MB fp4 frag file (w)

    pack_all_kernel<<<3072, 256, 0, stream>>>(x, w, xs, wsg, partials);
    finalize_kernel<<<1, 256, 0, stream>>>(partials, 2048, partials + 2048, 1024, red);

    dim3 grid((N_ROWS / 256) * (C_OUT / 256));  // 512
    xnor_gemm_fp4<<<grid, 512, 0, stream>>>(xs, wsg, bias, red, out);
}